// Round 5
// baseline (126.538 us; speedup 1.0000x reference)
//
#include <hip/hip_runtime.h>

// TT-linear: y = x[16384,784] @ W[784,512] + bias; out = softmax(relu(y), axis=1)
// prep_all: 225 blocks build W (bf16, MFMA B-fragment layout) from TT cores.
// tt_gemm : chunked double-buffered A staging (5 chunks x 5 k-tiles) overlapped
//           with the MFMA K-loop; B per-tile from L2; fused bias+relu+softmax.
//
// ws: [0, 819200) Wp bf16, idx = ((tn*25+tk)*64 + lane)*8 + j
//     = W[k=tk*32+quad*8+j][n=tn*16+lid]   (lane = quad*16+lid)

typedef __attribute__((ext_vector_type(8))) short short8;
typedef __attribute__((ext_vector_type(4))) float floatx4;

__device__ __forceinline__ unsigned int pack2_bf16(float a, float b) {
    unsigned int ua = __float_as_uint(a);
    unsigned int ub = __float_as_uint(b);
    return ((ub + 0x8000u) & 0xFFFF0000u) | ((ua + 0x8000u) >> 16);
}

__device__ __forceinline__ short f32_to_bf16_rne(float v) {
    unsigned int u = __float_as_uint(v);
    return (short)(((u + 0x7FFFu + ((u >> 16) & 1)) >> 16) & 0xFFFF);
}

// ---------- prep: t12 -> t123 slice -> wp slice, 225 blocks x 256 ----------
__global__ void prep_all(const float* __restrict__ c1, const float* __restrict__ c2,
                         const float* __restrict__ c3, const float* __restrict__ c4,
                         short* __restrict__ wp) {
    const int tid = threadIdx.x;
    const int blk = blockIdx.x;
    if (blk == 224) {                      // zero wp for k in [784,800)
        for (int e = tid; e < 8192; e += 256) {
            int j   = e & 7;
            int lid = (e >> 3) & 15;
            int q2  = (e >> 7) & 1;
            int tn  = e >> 8;
            wp[(((tn * 25 + 24) * 64 + (2 + q2) * 16 + lid) << 3) + j] = 0;
        }
        return;
    }
    __shared__ float t12s[320];            // [pq(16)][s(20)]
    __shared__ float t123s[7 * 256];       // [k3(7)][pql(16)][t(16)], pql=qloc*8+e3
    __shared__ float c4s[256];             // [t(16)][l(4)][f4(4)]

    const int ij    = blk >> 3;
    const int strip = blk & 7;
    const int i  = ij >> 2, j2 = ij & 3;
    const int p  = strip >> 1;
    const int qh = strip & 1;

    if (tid < 256) c4s[tid] = c4[tid];
    for (int e = tid; e < 320; e += 256) {
        int s = e % 20, pq = e / 20;
        int pp = pq >> 2, q = pq & 3;
        float acc = 0.f;
        #pragma unroll
        for (int r = 0; r < 20; ++r)
            acc += c1[i * 80 + pp * 20 + r] * c2[r * 320 + j2 * 80 + q * 20 + s];
        t12s[e] = acc;
    }
    __syncthreads();

    for (int e = tid; e < 1792; e += 256) {
        int k3 = e >> 8, li = e & 255;
        int t = li & 15, pql = li >> 4;
        int qloc = pql >> 3, e3 = pql & 7;
        int q = 2 * qh + qloc;
        float acc = 0.f;
        const float* tp = t12s + (p * 4 + q) * 20;
        const float* cp = c3 + k3 * 128 + e3 * 16 + t;
        #pragma unroll
        for (int s = 0; s < 20; ++s) acc += tp[s] * cp[s * 896];
        t123s[e] = acc;
    }
    __syncthreads();

    for (int e = tid; e < 1792; e += 256) {
        int kl = e >> 6, nl = e & 63;
        int k = ij * 28 + kl;
        int n = strip * 64 + nl;
        int k3 = kl >> 2, l = kl & 3;
        int f4 = n & 3, e3 = (n >> 2) & 7;
        int pql = ((n >> 5) & 1) * 8 + e3;
        const float* tp = t123s + k3 * 256 + pql * 16;
        const float* cq = c4s + l * 4 + f4;
        float a = 0.f;
        #pragma unroll
        for (int t = 0; t < 16; ++t) a += tp[t] * cq[t * 16];
        int tk = k >> 5, quad = (k >> 3) & 3, j = k & 7;
        int tn = n >> 4, lid = n & 15;
        wp[(((tn * 25 + tk) * 64 + quad * 16 + lid) << 3) + j] = f32_to_bf16_rne(a);
    }
}

// ---------- main GEMM + bias + relu + softmax ----------
// grid 512 (32 rows each), block 512 = 8 waves; wave w owns cols [w*64, w*64+64).
// K split into 5 chunks of 5 tiles. A-LDS double-buffered per chunk; chunk c's
// body: issue global loads for chunk c+1 -> MFMA chunk c (A from LDS, B from
// L2, barrier-free) -> pack+ds_write chunk c+1 -> one barrier.
__global__ __launch_bounds__(512, 4) void tt_gemm(const float* __restrict__ x,
                                                  const short* __restrict__ wp,
                                                  const float* __restrict__ bias,
                                                  float* __restrict__ out) {
    __shared__ __align__(16) short s_a[2][640 * 8];   // 2 x 10.24 KB
    __shared__ float part[8][32];

    const int tid  = threadIdx.x;
    const int w    = tid >> 6;
    const int lane = tid & 63;
    const int quad = lane >> 4;
    const int lid  = lane & 15;
    const int m_base = blockIdx.x * 32;
    const bool two = (tid < 128);          // waves 0,1 stage a second entry

    const short* wpw = wp + ((size_t)(w * 4) * 25 * 64 + lane) * 8;   // tn = w*4 + nt

    // entry e (0..639) of chunk c -> (row, k-base); layout: e = tl*128 + mt*64 + quad*16 + lid
    auto stage_load = [&](int c, int e, floatx4& v0, floatx4& v1) {
        const int row = ((e >> 6) & 1) * 16 + (e & 15);
        const int kc  = ((c * 5 + (e >> 7)) * 4 + ((e >> 4) & 3)) * 8;
        v0 = floatx4{0.f, 0.f, 0.f, 0.f};
        v1 = floatx4{0.f, 0.f, 0.f, 0.f};
        if (kc < 784) {
            const floatx4* p = (const floatx4*)(x + (size_t)(m_base + row) * 784 + kc);
            v0 = p[0]; v1 = p[1];
        }
    };
    auto stage_write = [&](int buf, int e, floatx4 v0, floatx4 v1) {
        union { short8 s; unsigned int u[4]; } af;
        af.u[0] = pack2_bf16(v0.x, v0.y);
        af.u[1] = pack2_bf16(v0.z, v0.w);
        af.u[2] = pack2_bf16(v1.x, v1.y);
        af.u[3] = pack2_bf16(v1.z, v1.w);
        *(short8*)&s_a[buf][e * 8] = af.s;
    };

    // ---- prologue: stage chunk 0 into buffer 0 ----
    {
        floatx4 a0, a1, b0, b1;
        stage_load(0, tid, a0, a1);
        if (two) stage_load(0, 512 + tid, b0, b1);
        stage_write(0, tid, a0, a1);
        if (two) stage_write(0, 512 + tid, b0, b1);
    }
    __syncthreads();

    floatx4 acc[2][4];
    #pragma unroll
    for (int mt = 0; mt < 2; ++mt)
        #pragma unroll
        for (int nt = 0; nt < 4; ++nt)
            acc[mt][nt] = floatx4{0.f, 0.f, 0.f, 0.f};

    #pragma unroll
    for (int c = 0; c < 5; ++c) {
        floatx4 p0, p1, q0, q1;
        if (c + 1 < 5) {                      // issue next chunk's global loads now
            stage_load(c + 1, tid, p0, p1);
            if (two) stage_load(c + 1, 512 + tid, q0, q1);
        }

        const short* sab = &s_a[c & 1][lane * 8];
        #pragma unroll
        for (int tl = 0; tl < 5; ++tl) {
            short8 a0 = *(const short8*)(sab + (size_t)(tl * 128) * 8);
            short8 a1 = *(const short8*)(sab + (size_t)(tl * 128 + 64) * 8);
            const int tk = c * 5 + tl;
            #pragma unroll
            for (int nt = 0; nt < 4; ++nt) {
                short8 bf = *(const short8*)(wpw + (size_t)(nt * 25 + tk) * 64 * 8);
                acc[0][nt] = __builtin_amdgcn_mfma_f32_16x16x32_bf16(a0, bf, acc[0][nt], 0, 0, 0);
                acc[1][nt] = __builtin_amdgcn_mfma_f32_16x16x32_bf16(a1, bf, acc[1][nt], 0, 0, 0);
            }
        }

        if (c + 1 < 5) {                      // pack + write next chunk, then sync
            stage_write((c + 1) & 1, tid, p0, p1);
            if (two) stage_write((c + 1) & 1, 512 + tid, q0, q1);
            __syncthreads();
        }
    }

    // ---- epilogue: bias + relu + exp, row sums across 8 waves, scale, store ----
    float bias_v[4];
    #pragma unroll
    for (int nt = 0; nt < 4; ++nt)
        bias_v[nt] = bias[w * 64 + nt * 16 + lid];

    #pragma unroll
    for (int mt = 0; mt < 2; ++mt) {
        #pragma unroll
        for (int reg = 0; reg < 4; ++reg) {
            float s = 0.f;
            #pragma unroll
            for (int nt = 0; nt < 4; ++nt) {
                float v = acc[mt][nt][reg] + bias_v[nt];
                v = fmaxf(v, 0.f);
                float e = __expf(v);
                acc[mt][nt][reg] = e;
                s += e;
            }
            s += __shfl_xor(s, 1, 64);
            s += __shfl_xor(s, 2, 64);
            s += __shfl_xor(s, 4, 64);
            s += __shfl_xor(s, 8, 64);
            if (lid == 0) part[w][mt * 16 + quad * 4 + reg] = s;
        }
    }
    __syncthreads();

    #pragma unroll
    for (int mt = 0; mt < 2; ++mt) {
        #pragma unroll
        for (int reg = 0; reg < 4; ++reg) {
            const int row = mt * 16 + quad * 4 + reg;
            float tot = 0.f;
            #pragma unroll
            for (int ww = 0; ww < 8; ++ww) tot += part[ww][row];
            const float inv = 1.0f / tot;
            #pragma unroll
            for (int nt = 0; nt < 4; ++nt)
                out[(size_t)(m_base + row) * 512 + w * 64 + nt * 16 + lid] = acc[mt][nt][reg] * inv;
        }
    }
}

extern "C" void kernel_launch(void* const* d_in, const int* in_sizes, int n_in,
                              void* d_out, int out_size, void* d_ws, size_t ws_size,
                              hipStream_t stream) {
    const float* x    = (const float*)d_in[0];
    const float* c1   = (const float*)d_in[1];
    const float* c2   = (const float*)d_in[2];
    const float* c3   = (const float*)d_in[3];
    const float* c4   = (const float*)d_in[4];
    const float* bias = (const float*)d_in[5];
    float* out = (float*)d_out;
    short* wpb = (short*)d_ws;

    prep_all<<<225, 256, 0, stream>>>(c1, c2, c3, c4, wpb);
    tt_gemm <<<512, 512, 0, stream>>>(x, wpb, bias, out);
}